// Round 4
// baseline (442.585 us; speedup 1.0000x reference)
//
#include <hip/hip_runtime.h>

// Problem constants (from reference): T=100 time steps, B=256, F=4096.
// Output: [B, T, F] float32, 419.4 MB. Write-bandwidth-bound.
// Floor: ~419 MB / 6.3 TB/s ≈ 67 us (harness fill proves this on d_out).
constexpr int T = 100;
constexpr int B = 256;
constexpr int F = 4096;
constexpr int F4 = F / 4;   // float4 granularity along F

typedef float floatx4 __attribute__((ext_vector_type(4)));

// R4: LINEAR-SWEEP layout. R3 showed the column-walk kernel (one thread per
// (b,f4), t-loop with 16 KB stride) runs at ~3 TB/s — scattered instantaneous
// write footprint kills DRAM page locality. Here: one thread per output
// float4, global thread id == flat f4-address of the output. The store stream
// is exactly fillBufferAligned's linear sweep (which hits 6.34 TB/s).
// x/delays are re-read per t but live in a 32 KB/b-slice working set -> L1/L2.
__global__ __launch_bounds__(256) void spike_kernel(
    const float* __restrict__ x,
    const float* __restrict__ delays,
    float* __restrict__ out)
{
    const int idx = blockIdx.x * blockDim.x + threadIdx.x;  // 0 .. B*T*F4-1
    const int f4  = idx & (F4 - 1);          // fastest: f4 (1024 per (b,t))
    const int bt  = idx >> 10;               // b*T + t
    const int t   = bt % T;                  // compiler: magic-mul, no divide
    const int b   = bt / T;

    const floatx4 xv = reinterpret_cast<const floatx4*>(x)[b * F4 + f4];
    const floatx4 dv = reinterpret_cast<const floatx4*>(delays)[f4];

    // Match numpy float32 semantics exactly: separate mul / sub / mul with
    // round-to-nearest, NO fma contraction (would shift st by 1 near integer
    // boundaries). Then trunc-toward-zero cast and clip to [0, T-1].
    auto spike_time = [](float xi, float di) -> int {
        float p  = __fmul_rn(xi, di);
        float s  = __fsub_rn(1.0f, p);
        float v  = __fmul_rn(s, 99.0f);   // (T-1) = 99
        int   st = (int)v;                 // trunc toward zero
        st = st < 0 ? 0 : st;
        st = st > (T - 1) ? (T - 1) : st;
        return st;
    };

    floatx4 v;
    v.x = (t == spike_time(xv.x, dv.x)) ? 1.0f : 0.0f;
    v.y = (t == spike_time(xv.y, dv.y)) ? 1.0f : 0.0f;
    v.z = (t == spike_time(xv.z, dv.z)) ? 1.0f : 0.0f;
    v.w = (t == spike_time(xv.w, dv.w)) ? 1.0f : 0.0f;

    // Store is exactly linear in idx: wave writes 1 KB contiguous, block 4 KB,
    // grid sweeps 419 MB front-to-back like the 6.3 TB/s fill kernel.
    reinterpret_cast<floatx4*>(out)[idx] = v;
}

extern "C" void kernel_launch(void* const* d_in, const int* in_sizes, int n_in,
                              void* d_out, int out_size, void* d_ws, size_t ws_size,
                              hipStream_t stream)
{
    const float* x      = reinterpret_cast<const float*>(d_in[0]);   // [B, F]
    const float* delays = reinterpret_cast<const float*>(d_in[1]);   // [F]
    float* out          = reinterpret_cast<float*>(d_out);           // [B, T, F]

    const int n_threads = B * T * F4;      // 26.2M threads, one per out float4
    const int block = 256;
    const int grid  = n_threads / block;   // 102400 blocks
    spike_kernel<<<grid, block, 0, stream>>>(x, delays, out);
}

// Round 5
// 413.397 us; speedup vs baseline: 1.0706x; 1.0706x over previous
//
#include <hip/hip_runtime.h>

// Problem constants (from reference): T=100 time steps, B=256, F=4096.
// Output: [B, T, F] float32, 419.4 MB. Write-bandwidth-bound.
// Floor: ~419 MB / 6.3 TB/s ≈ 67 us.
//
// R5 design: hybrid of R3 (load amortization) and R4 (linear store stream).
// Block = 1024 threads owns (b, 25 consecutive t, full F):
//   - each thread loads x[b, 4 floats] + delays[4 floats] ONCE (float4 each),
//     amortized over 25 stores -> load traffic ~ 1/25 of store traffic.
//   - per t-step the block stores 1024 x float4 = 16 KB CONTIGUOUS; 25 steps
//     walk a 400 KB linear region. Globally blocks tile the output linearly.
// This is optimal under both candidate models of R3's residual (write-page
// locality vs already-at-floor).
constexpr int T  = 100;
constexpr int B  = 256;
constexpr int F  = 4096;
constexpr int F4 = F / 4;       // 1024 float4 per (b,t) row
constexpr int TC = 25;          // t-chunk per block (T/4)

typedef float floatx4 __attribute__((ext_vector_type(4)));

__global__ __launch_bounds__(1024) void spike_kernel(
    const float* __restrict__ x,
    const float* __restrict__ delays,
    float* __restrict__ out)
{
    const int tid = threadIdx.x;          // 0..1023 == f4 index
    const int bb  = blockIdx.x;           // 0..B*4-1
    const int b   = bb >> 2;              // batch
    const int t0  = (bb & 3) * TC;        // start of this block's t-chunk

    const floatx4 xv = reinterpret_cast<const floatx4*>(x)[b * F4 + tid];
    const floatx4 dv = reinterpret_cast<const floatx4*>(delays)[tid];

    // Match numpy float32 semantics exactly: separate mul / sub / mul with
    // round-to-nearest, NO fma contraction (would shift st by 1 near integer
    // boundaries). Then trunc-toward-zero cast and clip to [0, T-1].
    auto spike_time = [](float xi, float di) -> int {
        float p  = __fmul_rn(xi, di);
        float s  = __fsub_rn(1.0f, p);
        float v  = __fmul_rn(s, 99.0f);   // (T-1) = 99
        int   st = (int)v;                 // trunc toward zero
        st = st < 0 ? 0 : st;
        st = st > (T - 1) ? (T - 1) : st;
        return st;
    };

    const int st0 = spike_time(xv.x, dv.x);
    const int st1 = spike_time(xv.y, dv.y);
    const int st2 = spike_time(xv.z, dv.z);
    const int st3 = spike_time(xv.w, dv.w);

    // Block's store region: out4[(b*T + t0 .. t0+24) * F4 + tid] — 25 steps of
    // 16 KB contiguous block-writes, 400 KB linear per block.
    floatx4* outp = reinterpret_cast<floatx4*>(out)
                  + (size_t)(b * T + t0) * F4 + tid;

#pragma unroll 5
    for (int i = 0; i < TC; ++i) {
        const int t = t0 + i;
        floatx4 v;
        v.x = (t == st0) ? 1.0f : 0.0f;
        v.y = (t == st1) ? 1.0f : 0.0f;
        v.z = (t == st2) ? 1.0f : 0.0f;
        v.w = (t == st3) ? 1.0f : 0.0f;
        outp[(size_t)i * F4] = v;
    }
}

extern "C" void kernel_launch(void* const* d_in, const int* in_sizes, int n_in,
                              void* d_out, int out_size, void* d_ws, size_t ws_size,
                              hipStream_t stream)
{
    const float* x      = reinterpret_cast<const float*>(d_in[0]);   // [B, F]
    const float* delays = reinterpret_cast<const float*>(d_in[1]);   // [F]
    float* out          = reinterpret_cast<float*>(d_out);           // [B, T, F]

    const int block = 1024;
    const int grid  = B * 4;               // 1024 blocks, 4 t-chunks per batch
    spike_kernel<<<grid, block, 0, stream>>>(x, delays, out);
}